// Round 1
// baseline (373.323 us; speedup 1.0000x reference)
//
#include <hip/hip_runtime.h>
#include <math.h>

#define BB 4
#define CC 32
#define HWSZ (512*512)
#define NMAX 128          // max instances supported (actual N=100 read at runtime)
#define NP 132            // padded LDS stride for [c][n]: bank=(4c+n)%32, spread by n
#define PPB 2048          // pixels per block
#define CHUNKS (HWSZ / PPB)   // 128 chunks per batch
#define DELTA_VAR_C 0.75f
#define DELTA_DIST_C 2.0f
#define GAMMA_C 0.001f

// block reduce over 256 threads (4 waves of 64); result valid on tid==0
__device__ __forceinline__ float block_reduce_256(float v, float* red, int tid) {
    #pragma unroll
    for (int o = 32; o > 0; o >>= 1) v += __shfl_down(v, o, 64);
    if ((tid & 63) == 0) red[tid >> 6] = v;
    __syncthreads();
    if (tid == 0) v = red[0] + red[1] + red[2] + red[3];
    return v;
}

// ---------------- Kernel 1: per-(batch,instance) sums + counts ----------------
__global__ __launch_bounds__(256) void k_seg_sum(
    const float* __restrict__ in, const int* __restrict__ lbl,
    const int* __restrict__ n_ptr, float* __restrict__ sums,
    float* __restrict__ counts)
{
    const int N = *n_ptr;
    __shared__ float s_sum[CC * NP];
    __shared__ float s_cnt[NMAX];
    const int tid = threadIdx.x;

    for (int i = tid; i < CC * NP; i += 256) s_sum[i] = 0.f;
    for (int i = tid; i < NMAX; i += 256) s_cnt[i] = 0.f;
    __syncthreads();

    const int chunk = blockIdx.x;
    const int b = chunk / CHUNKS;
    const int p0 = (chunk % CHUNKS) * PPB;

    const float* inb = in + (size_t)b * CC * HWSZ;
    const int* lb = lbl + (size_t)b * HWSZ + p0 + tid * 8;

    int4 l4a = *(const int4*)(lb);
    int4 l4b = *(const int4*)(lb + 4);
    int labels[8] = {l4a.x, l4a.y, l4a.z, l4a.w, l4b.x, l4b.y, l4b.z, l4b.w};

    #pragma unroll
    for (int i = 0; i < 8; i++) atomicAdd(&s_cnt[labels[i]], 1.0f);

    for (int c = 0; c < CC; ++c) {
        const float* inc = inb + (size_t)c * HWSZ + p0 + tid * 8;
        float4 a = *(const float4*)(inc);
        float4 b4 = *(const float4*)(inc + 4);
        float v[8] = {a.x, a.y, a.z, a.w, b4.x, b4.y, b4.z, b4.w};
        #pragma unroll
        for (int i = 0; i < 8; i++)
            atomicAdd(&s_sum[c * NP + labels[i]], v[i]);
    }
    __syncthreads();

    // flush block-private partials
    for (int i = tid; i < N * CC; i += 256) {
        int n = i / CC, c = i % CC;
        atomicAdd(&sums[(size_t)b * NMAX * CC + i], s_sum[c * NP + n]);
    }
    for (int i = tid; i < N; i += 256)
        atomicAdd(&counts[b * NMAX + i], s_cnt[i]);
}

// -------- Kernel 2: means, pairwise-distance term, regularization term --------
__global__ __launch_bounds__(256) void k_means_dist(
    const float* __restrict__ sums, const float* __restrict__ counts,
    const int* __restrict__ n_ptr, float* __restrict__ means,
    float* __restrict__ out)
{
    const int N = *n_ptr;
    const int b = blockIdx.x;
    __shared__ float m[NMAX * 33];   // [n][c], stride 33 -> bank (n+c)%32
    __shared__ float red[4];
    const int tid = threadIdx.x;

    for (int i = tid; i < N * CC; i += 256) {
        int n = i / CC, c = i % CC;
        float mu = sums[(size_t)b * NMAX * CC + i] / counts[b * NMAX + n];
        means[(size_t)b * NMAX * CC + i] = mu;
        m[n * 33 + c] = mu;
    }
    __syncthreads();

    float acc = 0.f;   // dist_sum*scale + reg_sum*scale folded below
    float dist_sum = 0.f;
    for (int pr = tid; pr < N * N; pr += 256) {
        int i = pr / N, j = pr - i * N;
        if (i == j) continue;
        float d2 = 0.f;
        #pragma unroll
        for (int c = 0; c < CC; c++) {
            float d = m[i * 33 + c] - m[j * 33 + c];
            d2 += d * d;
        }
        float dm = (d2 > 0.f) ? sqrtf(d2) : 1.0f;   // match jnp.where(d2>0,d2,1)
        float h = fmaxf(2.0f * DELTA_DIST_C - dm, 0.f);
        dist_sum += h * h;
    }
    float reg_sum = 0.f;
    for (int n = tid; n < N; n += 256) {
        float s = 0.f;
        #pragma unroll
        for (int c = 0; c < CC; c++) { float v = m[n * 33 + c]; s += v * v; }
        reg_sum += sqrtf(s);
    }
    acc = dist_sum / ((float)N * (float)(N - 1)) + reg_sum * (GAMMA_C / (float)N);
    float tot = block_reduce_256(acc, red, tid);
    if (tid == 0) atomicAdd(out, tot * (1.0f / (float)BB));
}

// ---------------- Kernel 3: variance (hinge) term, second pass ----------------
__global__ __launch_bounds__(256) void k_var(
    const float* __restrict__ in, const int* __restrict__ lbl,
    const int* __restrict__ n_ptr, const float* __restrict__ means,
    const float* __restrict__ counts, float* __restrict__ out)
{
    const int N = *n_ptr;
    __shared__ float m_t[CC * NP];   // [c][n] transposed, padded stride
    __shared__ float invc[NMAX];
    __shared__ float red[4];
    const int tid = threadIdx.x;

    const int chunk = blockIdx.x;
    const int b = chunk / CHUNKS;
    const int p0 = (chunk % CHUNKS) * PPB;

    for (int i = tid; i < N * CC; i += 256) {
        int n = i / CC, c = i % CC;
        m_t[c * NP + n] = means[(size_t)b * NMAX * CC + i];
    }
    for (int i = tid; i < N; i += 256)
        invc[i] = 1.0f / counts[b * NMAX + i];
    __syncthreads();

    const float* inb = in + (size_t)b * CC * HWSZ;
    const int* lb = lbl + (size_t)b * HWSZ + p0 + tid * 8;

    int4 l4a = *(const int4*)(lb);
    int4 l4b = *(const int4*)(lb + 4);
    int labels[8] = {l4a.x, l4a.y, l4a.z, l4a.w, l4b.x, l4b.y, l4b.z, l4b.w};
    float acc[8];
    #pragma unroll
    for (int i = 0; i < 8; i++) acc[i] = 0.f;

    for (int c = 0; c < CC; ++c) {
        const float* inc = inb + (size_t)c * HWSZ + p0 + tid * 8;
        float4 a = *(const float4*)(inc);
        float4 b4 = *(const float4*)(inc + 4);
        float v[8] = {a.x, a.y, a.z, a.w, b4.x, b4.y, b4.z, b4.w};
        #pragma unroll
        for (int i = 0; i < 8; i++) {
            float d = v[i] - m_t[c * NP + labels[i]];
            acc[i] += d * d;
        }
    }

    float vsum = 0.f;
    #pragma unroll
    for (int i = 0; i < 8; i++) {
        float nm = sqrtf(acc[i]);
        float t = fmaxf(nm - DELTA_VAR_C, 0.f);
        vsum += t * t * invc[labels[i]];
    }
    float tot = block_reduce_256(vsum, red, tid);
    if (tid == 0)
        atomicAdd(out, tot * (1.0f / ((float)N * (float)BB)));
}

extern "C" void kernel_launch(void* const* d_in, const int* in_sizes, int n_in,
                              void* d_out, int out_size, void* d_ws, size_t ws_size,
                              hipStream_t stream) {
    (void)in_sizes; (void)n_in; (void)out_size; (void)ws_size;
    const float* in  = (const float*)d_in[0];
    const int*   lbl = (const int*)d_in[1];
    const int*   n_ptr = (const int*)d_in[2];
    float* out = (float*)d_out;

    float* sums   = (float*)d_ws;                 // B*NMAX*C
    float* counts = sums + BB * NMAX * CC;        // B*NMAX
    float* means  = counts + BB * NMAX;           // B*NMAX*C

    hipMemsetAsync(d_ws, 0, (size_t)(BB * NMAX * CC + BB * NMAX) * sizeof(float), stream);
    hipMemsetAsync(d_out, 0, sizeof(float), stream);

    const int blocks = BB * CHUNKS;   // 512
    k_seg_sum<<<blocks, 256, 0, stream>>>(in, lbl, n_ptr, sums, counts);
    k_means_dist<<<BB, 256, 0, stream>>>(sums, counts, n_ptr, means, out);
    k_var<<<blocks, 256, 0, stream>>>(in, lbl, n_ptr, means, counts, out);
}

// Round 2
// 257.829 us; speedup vs baseline: 1.4479x; 1.4479x over previous
//
#include <hip/hip_runtime.h>
#include <math.h>

#define BB 4
#define CC 32
#define HWSZ (512*512)
#define NMAX 128              // max instances supported (actual N=100 at runtime)
#define NP 132                // padded LDS stride for [c][n]
#define PPB 1024              // pixels per block
#define CHUNKS (HWSZ / PPB)   // 256 chunks per batch
#define DELTA_VAR_C 0.75f
#define DELTA_DIST_C 2.0f
#define GAMMA_C 0.001f
#define FXS 1048576.0f        // fixed-point scale 2^20
#define FXI (1.0f / 1048576.0f)

// block reduce over 256 threads (4 waves of 64); result valid on tid==0
__device__ __forceinline__ float block_reduce_256(float v, float* red, int tid) {
    #pragma unroll
    for (int o = 32; o > 0; o >>= 1) v += __shfl_down(v, o, 64);
    if ((tid & 63) == 0) red[tid >> 6] = v;
    __syncthreads();
    if (tid == 0) v = red[0] + red[1] + red[2] + red[3];
    return v;
}

// ---------------- Kernel 1: per-(batch,instance) sums + counts (fixed-point) ----
__global__ __launch_bounds__(256) void k_seg_sum(
    const float* __restrict__ in, const int* __restrict__ lbl,
    const int* __restrict__ n_ptr, int* __restrict__ sums_i,
    unsigned int* __restrict__ counts_u)
{
    const int N = *n_ptr;
    __shared__ int s_sum[CC * NP];
    __shared__ unsigned int s_cnt[NMAX];
    const int tid = threadIdx.x;

    for (int i = tid; i < CC * NP; i += 256) s_sum[i] = 0;
    for (int i = tid; i < NMAX; i += 256) s_cnt[i] = 0u;
    __syncthreads();

    const int chunk = blockIdx.x;
    const int b = chunk / CHUNKS;
    const int p0 = (chunk % CHUNKS) * PPB;

    const float* inb = in + (size_t)b * CC * HWSZ;
    const int* lb = lbl + (size_t)b * HWSZ + p0 + tid * 4;

    int4 l4 = *(const int4*)(lb);
    int labels[4] = {l4.x, l4.y, l4.z, l4.w};

    #pragma unroll
    for (int i = 0; i < 4; i++) atomicAdd(&s_cnt[labels[i]], 1u);

    #pragma unroll 4
    for (int c = 0; c < CC; ++c) {
        const float* inc = inb + (size_t)c * HWSZ + p0 + tid * 4;
        float4 a = *(const float4*)(inc);
        float v[4] = {a.x, a.y, a.z, a.w};
        #pragma unroll
        for (int i = 0; i < 4; i++) {
            int q = (int)rintf(v[i] * FXS);
            atomicAdd(&s_sum[c * NP + labels[i]], q);
        }
    }
    __syncthreads();

    // flush block-private partials (native int atomics)
    for (int i = tid; i < N * CC; i += 256) {
        int n = i / CC, c = i % CC;
        int val = s_sum[c * NP + n];
        if (val != 0) atomicAdd(&sums_i[(size_t)b * NMAX * CC + i], val);
    }
    for (int i = tid; i < N; i += 256) {
        unsigned int cv = s_cnt[i];
        if (cv) atomicAdd(&counts_u[b * NMAX + i], cv);
    }
}

// -------- Kernel 2: means, pairwise-distance term, regularization term --------
__global__ __launch_bounds__(256) void k_means_dist(
    const int* __restrict__ sums_i, const unsigned int* __restrict__ counts_u,
    const int* __restrict__ n_ptr, float* __restrict__ means,
    int* __restrict__ out_acc)
{
    const int N = *n_ptr;
    const int b = blockIdx.x;
    __shared__ float m[NMAX * 33];   // [n][c], stride 33
    __shared__ float red[4];
    const int tid = threadIdx.x;

    for (int i = tid; i < N * CC; i += 256) {
        int n = i / CC;
        float mu = (float)sums_i[(size_t)b * NMAX * CC + i] * FXI
                 / (float)counts_u[b * NMAX + n];
        means[(size_t)b * NMAX * CC + i] = mu;
        m[n * 33 + (i % CC)] = mu;
    }
    __syncthreads();

    float dist_sum = 0.f;
    for (int pr = tid; pr < N * N; pr += 256) {
        int i = pr / N, j = pr - i * N;
        if (i == j) continue;
        float d2 = 0.f;
        #pragma unroll
        for (int c = 0; c < CC; c++) {
            float d = m[i * 33 + c] - m[j * 33 + c];
            d2 += d * d;
        }
        float dm = (d2 > 0.f) ? sqrtf(d2) : 1.0f;   // match jnp.where(d2>0,d2,1)
        float h = fmaxf(2.0f * DELTA_DIST_C - dm, 0.f);
        dist_sum += h * h;
    }
    float reg_sum = 0.f;
    for (int n = tid; n < N; n += 256) {
        float s = 0.f;
        #pragma unroll
        for (int c = 0; c < CC; c++) { float v = m[n * 33 + c]; s += v * v; }
        reg_sum += sqrtf(s);
    }
    float acc = dist_sum / ((float)N * (float)(N - 1)) + reg_sum * (GAMMA_C / (float)N);
    float tot = block_reduce_256(acc, red, tid);
    if (tid == 0)
        atomicAdd(out_acc, (int)rintf(tot * (1.0f / (float)BB) * FXS));
}

// ---------------- Kernel 3: variance (hinge) term, second pass ----------------
__global__ __launch_bounds__(256) void k_var(
    const float* __restrict__ in, const int* __restrict__ lbl,
    const int* __restrict__ n_ptr, const float* __restrict__ means,
    const unsigned int* __restrict__ counts_u, int* __restrict__ out_acc)
{
    const int N = *n_ptr;
    __shared__ float m_t[CC * NP];   // [c][n] transposed
    __shared__ float invc[NMAX];
    __shared__ float red[4];
    const int tid = threadIdx.x;

    const int chunk = blockIdx.x;
    const int b = chunk / CHUNKS;
    const int p0 = (chunk % CHUNKS) * PPB;

    for (int i = tid; i < N * CC; i += 256) {
        int n = i / CC, c = i % CC;
        m_t[c * NP + n] = means[(size_t)b * NMAX * CC + i];
    }
    for (int i = tid; i < N; i += 256)
        invc[i] = 1.0f / (float)counts_u[b * NMAX + i];
    __syncthreads();

    const float* inb = in + (size_t)b * CC * HWSZ;
    const int* lb = lbl + (size_t)b * HWSZ + p0 + tid * 4;

    int4 l4 = *(const int4*)(lb);
    int labels[4] = {l4.x, l4.y, l4.z, l4.w};
    float acc[4] = {0.f, 0.f, 0.f, 0.f};

    #pragma unroll 4
    for (int c = 0; c < CC; ++c) {
        const float* inc = inb + (size_t)c * HWSZ + p0 + tid * 4;
        float4 a = *(const float4*)(inc);
        float v[4] = {a.x, a.y, a.z, a.w};
        #pragma unroll
        for (int i = 0; i < 4; i++) {
            float d = v[i] - m_t[c * NP + labels[i]];
            acc[i] += d * d;
        }
    }

    float vsum = 0.f;
    #pragma unroll
    for (int i = 0; i < 4; i++) {
        float nm = sqrtf(acc[i]);
        float t = fmaxf(nm - DELTA_VAR_C, 0.f);
        vsum += t * t * invc[labels[i]];
    }
    float tot = block_reduce_256(vsum, red, tid);
    if (tid == 0)
        atomicAdd(out_acc, (int)rintf(tot * (1.0f / ((float)N * (float)BB)) * FXS));
}

// ---------------- Kernel 4: fixed-point -> float output ----------------
__global__ void k_final(const int* __restrict__ out_acc, float* __restrict__ out) {
    if (threadIdx.x == 0 && blockIdx.x == 0)
        *out = (float)(*out_acc) * FXI;
}

extern "C" void kernel_launch(void* const* d_in, const int* in_sizes, int n_in,
                              void* d_out, int out_size, void* d_ws, size_t ws_size,
                              hipStream_t stream) {
    (void)in_sizes; (void)n_in; (void)out_size; (void)ws_size;
    const float* in  = (const float*)d_in[0];
    const int*   lbl = (const int*)d_in[1];
    const int*   n_ptr = (const int*)d_in[2];
    float* out = (float*)d_out;

    int* sums_i = (int*)d_ws;                               // BB*NMAX*CC ints
    unsigned int* counts_u = (unsigned int*)(sums_i + BB * NMAX * CC); // BB*NMAX
    int* out_acc = (int*)(counts_u + BB * NMAX);            // 1 int
    float* means = (float*)(out_acc + 1);                   // BB*NMAX*CC floats

    hipMemsetAsync(d_ws, 0,
                   (size_t)(BB * NMAX * CC + BB * NMAX + 1) * sizeof(int), stream);

    const int blocks = BB * CHUNKS;   // 1024
    k_seg_sum<<<blocks, 256, 0, stream>>>(in, lbl, n_ptr, sums_i, counts_u);
    k_means_dist<<<BB, 256, 0, stream>>>(sums_i, counts_u, n_ptr, means, out_acc);
    k_var<<<blocks, 256, 0, stream>>>(in, lbl, n_ptr, means, counts_u, out_acc);
    k_final<<<1, 64, 0, stream>>>(out_acc, out);
}

// Round 3
// 235.664 us; speedup vs baseline: 1.5841x; 1.0941x over previous
//
#include <hip/hip_runtime.h>
#include <math.h>

#define BB 4
#define CC 32
#define HWSZ (512*512)
#define NMAX 128              // max instances supported (actual N=100 at runtime)
#define NP 132                // padded LDS stride for [c][n]
#define PPB 2048              // pixels per block
#define CHUNKS (HWSZ / PPB)   // 128 chunks per batch
#define DELTA_VAR_C 0.75f
#define DELTA_DIST_C 2.0f
#define GAMMA_C 0.001f
#define FXS 1048576.0f        // fixed-point scale 2^20
#define FXI (1.0f / 1048576.0f)

#define LD4(p) (*(const float4*)(p))

// block reduce over 256 threads (4 waves of 64); result valid on tid==0
__device__ __forceinline__ float block_reduce_256(float v, float* red, int tid) {
    #pragma unroll
    for (int o = 32; o > 0; o >>= 1) v += __shfl_down(v, o, 64);
    if ((tid & 63) == 0) red[tid >> 6] = v;
    __syncthreads();
    if (tid == 0) v = red[0] + red[1] + red[2] + red[3];
    return v;
}

// ---------------- Kernel 1: per-(batch,instance) sums + counts (fixed-point) ----
__global__ __launch_bounds__(256) void k_seg_sum(
    const float* __restrict__ in, const int* __restrict__ lbl,
    const int* __restrict__ n_ptr, int* __restrict__ sums_i,
    unsigned int* __restrict__ counts_u)
{
    const int N = *n_ptr;
    __shared__ int s_sum[CC * NP];
    __shared__ unsigned int s_cnt[NMAX];
    const int tid = threadIdx.x;

    for (int i = tid; i < CC * NP; i += 256) s_sum[i] = 0;
    for (int i = tid; i < NMAX; i += 256) s_cnt[i] = 0u;
    __syncthreads();

    const int b = blockIdx.x >> 7;            // / CHUNKS
    const int p0 = (blockIdx.x & (CHUNKS - 1)) * PPB;

    const float* inb = in + (size_t)b * CC * HWSZ;
    const int* lb = lbl + (size_t)b * HWSZ + p0 + tid * 8;

    int4 l4a = *(const int4*)(lb);
    int4 l4b = *(const int4*)(lb + 4);
    int lab[8] = {l4a.x, l4a.y, l4a.z, l4a.w, l4b.x, l4b.y, l4b.z, l4b.w};

    #pragma unroll
    for (int i = 0; i < 8; i++) atomicAdd(&s_cnt[lab[i]], 1u);

    const float* p = inb + p0 + (size_t)tid * 8;
    // 4-deep pipelined loads: channels c and c+1 in flight while processing
    float4 a0 = LD4(p);            float4 b0 = LD4(p + 4);
    float4 a1 = LD4(p + HWSZ);     float4 b1 = LD4(p + HWSZ + 4);

    for (int c = 0; c < CC; c += 2) {
        float4 ca0 = a0, cb0 = b0, ca1 = a1, cb1 = b1;
        if (c + 2 < CC) {
            const float* q = p + (size_t)(c + 2) * HWSZ;
            a0 = LD4(q);          b0 = LD4(q + 4);
            a1 = LD4(q + HWSZ);   b1 = LD4(q + HWSZ + 4);
        }
        float v0[8] = {ca0.x, ca0.y, ca0.z, ca0.w, cb0.x, cb0.y, cb0.z, cb0.w};
        #pragma unroll
        for (int i = 0; i < 8; i++)
            atomicAdd(&s_sum[c * NP + lab[i]], (int)rintf(v0[i] * FXS));
        float v1[8] = {ca1.x, ca1.y, ca1.z, ca1.w, cb1.x, cb1.y, cb1.z, cb1.w};
        #pragma unroll
        for (int i = 0; i < 8; i++)
            atomicAdd(&s_sum[(c + 1) * NP + lab[i]], (int)rintf(v1[i] * FXS));
    }
    __syncthreads();

    // flush block-private partials (native int atomics)
    for (int i = tid; i < N * CC; i += 256) {
        int n = i / CC, c = i % CC;
        int val = s_sum[c * NP + n];
        if (val != 0) atomicAdd(&sums_i[(size_t)b * NMAX * CC + i], val);
    }
    for (int i = tid; i < N; i += 256) {
        unsigned int cv = s_cnt[i];
        if (cv) atomicAdd(&counts_u[b * NMAX + i], cv);
    }
}

// ---------------- Kernel 2a: means ----------------
__global__ __launch_bounds__(256) void k_means(
    const int* __restrict__ sums_i, const unsigned int* __restrict__ counts_u,
    const int* __restrict__ n_ptr, float* __restrict__ means)
{
    const int N = *n_ptr;
    const int b = blockIdx.x;
    const int tid = threadIdx.x;
    for (int i = tid; i < N * CC; i += 256) {
        int n = i / CC;
        float mu = (float)sums_i[(size_t)b * NMAX * CC + i] * FXI
                 / (float)counts_u[b * NMAX + n];
        means[(size_t)b * NMAX * CC + i] = mu;
    }
}

// ------- Kernel 2b: pairwise-distance term + regularization term (sliced) -----
#define DSLICE 8
__global__ __launch_bounds__(256) void k_dist(
    const float* __restrict__ means, const int* __restrict__ n_ptr,
    int* __restrict__ out_acc)
{
    const int N = *n_ptr;
    const int b = blockIdx.x / DSLICE;
    const int slice = blockIdx.x % DSLICE;
    __shared__ float m[NMAX * 33];   // [n][c], stride 33
    __shared__ float red[4];
    const int tid = threadIdx.x;

    for (int i = tid; i < N * CC; i += 256)
        m[(i / CC) * 33 + (i % CC)] = means[(size_t)b * NMAX * CC + i];
    __syncthreads();

    float dist_sum = 0.f;
    for (int pr = slice * 256 + tid; pr < N * N; pr += DSLICE * 256) {
        int i = pr / N, j = pr - i * N;
        if (i == j) continue;
        float d2 = 0.f;
        #pragma unroll
        for (int c = 0; c < CC; c++) {
            float d = m[i * 33 + c] - m[j * 33 + c];
            d2 += d * d;
        }
        float dm = (d2 > 0.f) ? sqrtf(d2) : 1.0f;   // match jnp.where(d2>0,d2,1)
        float h = fmaxf(2.0f * DELTA_DIST_C - dm, 0.f);
        dist_sum += h * h;
    }
    float acc = dist_sum / ((float)N * (float)(N - 1));
    if (slice == 0) {
        float reg_sum = 0.f;
        for (int n = tid; n < N; n += 256) {
            float s = 0.f;
            #pragma unroll
            for (int c = 0; c < CC; c++) { float v = m[n * 33 + c]; s += v * v; }
            reg_sum += sqrtf(s);
        }
        acc += reg_sum * (GAMMA_C / (float)N);
    }
    float tot = block_reduce_256(acc, red, tid);
    if (tid == 0)
        atomicAdd(out_acc, (int)rintf(tot * (1.0f / (float)BB) * FXS));
}

// ---------------- Kernel 3: variance (hinge) term, second pass ----------------
__global__ __launch_bounds__(256) void k_var(
    const float* __restrict__ in, const int* __restrict__ lbl,
    const int* __restrict__ n_ptr, const float* __restrict__ means,
    const unsigned int* __restrict__ counts_u, int* __restrict__ out_acc)
{
    const int N = *n_ptr;
    __shared__ float m_t[CC * NP];   // [c][n] transposed
    __shared__ float invc[NMAX];
    __shared__ float red[4];
    const int tid = threadIdx.x;

    const int b = blockIdx.x >> 7;
    const int p0 = (blockIdx.x & (CHUNKS - 1)) * PPB;

    for (int i = tid; i < N * CC; i += 256) {
        int n = i / CC, c = i % CC;
        m_t[c * NP + n] = means[(size_t)b * NMAX * CC + i];
    }
    for (int i = tid; i < N; i += 256)
        invc[i] = 1.0f / (float)counts_u[b * NMAX + i];
    __syncthreads();

    const float* inb = in + (size_t)b * CC * HWSZ;
    const int* lb = lbl + (size_t)b * HWSZ + p0 + tid * 8;

    int4 l4a = *(const int4*)(lb);
    int4 l4b = *(const int4*)(lb + 4);
    int lab[8] = {l4a.x, l4a.y, l4a.z, l4a.w, l4b.x, l4b.y, l4b.z, l4b.w};
    float acc[8] = {0.f, 0.f, 0.f, 0.f, 0.f, 0.f, 0.f, 0.f};

    const float* p = inb + p0 + (size_t)tid * 8;
    float4 a0 = LD4(p);            float4 b0 = LD4(p + 4);
    float4 a1 = LD4(p + HWSZ);     float4 b1 = LD4(p + HWSZ + 4);

    for (int c = 0; c < CC; c += 2) {
        float4 ca0 = a0, cb0 = b0, ca1 = a1, cb1 = b1;
        if (c + 2 < CC) {
            const float* q = p + (size_t)(c + 2) * HWSZ;
            a0 = LD4(q);          b0 = LD4(q + 4);
            a1 = LD4(q + HWSZ);   b1 = LD4(q + HWSZ + 4);
        }
        float v0[8] = {ca0.x, ca0.y, ca0.z, ca0.w, cb0.x, cb0.y, cb0.z, cb0.w};
        #pragma unroll
        for (int i = 0; i < 8; i++) {
            float d = v0[i] - m_t[c * NP + lab[i]];
            acc[i] += d * d;
        }
        float v1[8] = {ca1.x, ca1.y, ca1.z, ca1.w, cb1.x, cb1.y, cb1.z, cb1.w};
        #pragma unroll
        for (int i = 0; i < 8; i++) {
            float d = v1[i] - m_t[(c + 1) * NP + lab[i]];
            acc[i] += d * d;
        }
    }

    float vsum = 0.f;
    #pragma unroll
    for (int i = 0; i < 8; i++) {
        float nm = sqrtf(acc[i]);
        float t = fmaxf(nm - DELTA_VAR_C, 0.f);
        vsum += t * t * invc[lab[i]];
    }
    float tot = block_reduce_256(vsum, red, tid);
    if (tid == 0)
        atomicAdd(out_acc, (int)rintf(tot * (1.0f / ((float)N * (float)BB)) * FXS));
}

// ---------------- Kernel 4: fixed-point -> float output ----------------
__global__ void k_final(const int* __restrict__ out_acc, float* __restrict__ out) {
    if (threadIdx.x == 0 && blockIdx.x == 0)
        *out = (float)(*out_acc) * FXI;
}

extern "C" void kernel_launch(void* const* d_in, const int* in_sizes, int n_in,
                              void* d_out, int out_size, void* d_ws, size_t ws_size,
                              hipStream_t stream) {
    (void)in_sizes; (void)n_in; (void)out_size; (void)ws_size;
    const float* in  = (const float*)d_in[0];
    const int*   lbl = (const int*)d_in[1];
    const int*   n_ptr = (const int*)d_in[2];
    float* out = (float*)d_out;

    int* sums_i = (int*)d_ws;                                          // BB*NMAX*CC
    unsigned int* counts_u = (unsigned int*)(sums_i + BB * NMAX * CC); // BB*NMAX
    int* out_acc = (int*)(counts_u + BB * NMAX);                       // 1
    float* means = (float*)(out_acc + 1);                              // BB*NMAX*CC

    hipMemsetAsync(d_ws, 0,
                   (size_t)(BB * NMAX * CC + BB * NMAX + 1) * sizeof(int), stream);

    const int blocks = BB * CHUNKS;   // 512
    k_seg_sum<<<blocks, 256, 0, stream>>>(in, lbl, n_ptr, sums_i, counts_u);
    k_means<<<BB, 256, 0, stream>>>(sums_i, counts_u, n_ptr, means);
    k_var<<<blocks, 256, 0, stream>>>(in, lbl, n_ptr, means, counts_u, out_acc);
    k_dist<<<BB * DSLICE, 256, 0, stream>>>(means, n_ptr, out_acc);
    k_final<<<1, 64, 0, stream>>>(out_acc, out);
}